// Round 1
// baseline (1871.296 us; speedup 1.0000x reference)
//
#include <hip/hip_runtime.h>
#include <stdint.h>

// MHA: B=4 S=2048 DM=1024 H=16 DK=64
// out = (output [4,2048,1024] f32, attn [4,16,2048,2048] f32) concat flat.

typedef short bf16x8 __attribute__((ext_vector_type(8)));
typedef float f32x4 __attribute__((ext_vector_type(4)));
typedef unsigned short u16x4 __attribute__((ext_vector_type(4)));
typedef unsigned short u16x8 __attribute__((ext_vector_type(8)));

__device__ __forceinline__ unsigned short f2bf(float f) {
  union { float f; uint32_t u; } v; v.f = f;
  uint32_t u = v.u;
  u += 0x7fffu + ((u >> 16) & 1u);   // RNE
  return (unsigned short)(u >> 16);
}

// ---------------- stage 1: f32 -> bf16 casts ----------------
__global__ void cast_kernel(const float* __restrict__ src,
                            unsigned short* __restrict__ dst, int n4) {
  int i = blockIdx.x * blockDim.x + threadIdx.x;
  int stride = gridDim.x * blockDim.x;
  for (; i < n4; i += stride) {
    float4 v = ((const float4*)src)[i];
    u16x4 o;
    o.x = f2bf(v.x); o.y = f2bf(v.y); o.z = f2bf(v.z); o.w = f2bf(v.w);
    ((u16x4*)dst)[i] = o;
  }
}

// ---------------- stage 2: QKV projection GEMM ----------------
// C[8192,3072] = Xbf[8192,1024] * Wall[3072,1024]^T ; scatter into
// q[b,h,s,dk], k[b,h,s,dk], vt[b,h,dk,s] (bf16).
__global__ __launch_bounds__(256) void gemm_qkv(
    const unsigned short* __restrict__ A,
    const unsigned short* __restrict__ W,
    unsigned short* __restrict__ qout,
    unsigned short* __restrict__ kout,
    unsigned short* __restrict__ vtout)
{
  __shared__ unsigned short aT[128 * 64];
  __shared__ unsigned short bT[128 * 64];
  const int tid = threadIdx.x;
  const int l = tid & 63, w = tid >> 6;
  const int wr = (w >> 1) * 64, wc = (w & 1) * 64;
  const int g = l >> 4, c = l & 15;
  const int tM = blockIdx.x, tN = blockIdx.y;
  const int srow = tid >> 3, scol = (tid & 7) * 8;
  const unsigned short* ga = A + (size_t)(tM * 128 + srow) * 1024 + scol;
  const unsigned short* gb = W + (size_t)(tN * 128 + srow) * 1024 + scol;
  f32x4 acc[4][4] = {};
  for (int kt = 0; kt < 16; ++kt) {
    u16x8 av[4], bv[4];
#pragma unroll
    for (int i = 0; i < 4; ++i) {
      av[i] = *(const u16x8*)(ga + kt * 64 + (size_t)i * 32 * 1024);
      bv[i] = *(const u16x8*)(gb + kt * 64 + (size_t)i * 32 * 1024);
    }
    __syncthreads();
#pragma unroll
    for (int i = 0; i < 4; ++i) {
      *(u16x8*)&aT[(srow + i * 32) * 64 + scol] = av[i];
      *(u16x8*)&bT[(srow + i * 32) * 64 + scol] = bv[i];
    }
    __syncthreads();
#pragma unroll
    for (int kk = 0; kk < 2; ++kk) {
      bf16x8 af[4], bf[4];
#pragma unroll
      for (int m = 0; m < 4; ++m)
        af[m] = *(const bf16x8*)&aT[(wr + m * 16 + c) * 64 + kk * 32 + g * 8];
#pragma unroll
      for (int n = 0; n < 4; ++n)
        bf[n] = *(const bf16x8*)&bT[(wc + n * 16 + c) * 64 + kk * 32 + g * 8];
#pragma unroll
      for (int m = 0; m < 4; ++m)
#pragma unroll
        for (int n = 0; n < 4; ++n)
          acc[m][n] = __builtin_amdgcn_mfma_f32_16x16x32_bf16(af[m], bf[n], acc[m][n], 0, 0, 0);
    }
  }
  const int proj = (tN * 128) >> 10;  // uniform per block (128 | 1024)
#pragma unroll
  for (int m = 0; m < 4; ++m) {
#pragma unroll
    for (int n = 0; n < 4; ++n) {
      const int row0 = tM * 128 + wr + m * 16 + g * 4;
      const int ncol = tN * 128 + wc + n * 16 + c;
      const int hh = (ncol & 1023) >> 6, dkk = ncol & 63;
      if (proj == 2) {
        const int b = row0 >> 11, s = row0 & 2047;
        u16x4 pk;
        pk.x = f2bf(acc[m][n][0]); pk.y = f2bf(acc[m][n][1]);
        pk.z = f2bf(acc[m][n][2]); pk.w = f2bf(acc[m][n][3]);
        *(u16x4*)&vtout[((size_t)((b * 16 + hh) * 64 + dkk)) * 2048 + s] = pk;
      } else {
        unsigned short* dst = (proj == 0) ? qout : kout;
#pragma unroll
        for (int r = 0; r < 4; ++r) {
          const int row = row0 + r;
          const int b = row >> 11, s = row & 2047;
          dst[((size_t)((b * 16 + hh) * 2048 + s)) * 64 + dkk] = f2bf(acc[m][n][r]);
        }
      }
    }
  }
}

// ---------------- stage 3: fused QK^T + softmax + attn write + PV ----------------
// 8 waves, q-tile = 16 rows, each wave owns a 256-key strip; scores in regs.
__global__ __launch_bounds__(512) void attn_kernel(
    const unsigned short* __restrict__ qm,
    const unsigned short* __restrict__ km,
    const unsigned short* __restrict__ vt,
    const int* __restrict__ mask,
    float* __restrict__ attn_out,
    unsigned short* __restrict__ concat)
{
  __shared__ float red_max[8][16];
  __shared__ float red_sum[8][16];
  __shared__ float hred[8][16][64];
  const int tid = threadIdx.x, w = tid >> 6, l = tid & 63;
  const int g = l >> 4, c = l & 15;
  const int qt = blockIdx.x, h = blockIdx.y, b = blockIdx.z;
  const int q0 = qt * 16;
  const size_t headoff = ((size_t)(b * 16 + h)) * 2048 * 64;
  const unsigned short* qh = qm + headoff;
  const unsigned short* kh = km + headoff;
  const unsigned short* vth = vt + headoff;  // [64][2048]
  const int nb = w * 256;

  bf16x8 qf[2];
#pragma unroll
  for (int kk = 0; kk < 2; ++kk)
    qf[kk] = *(const bf16x8*)&qh[(size_t)(q0 + c) * 64 + kk * 32 + g * 8];

  f32x4 sc[16];
#pragma unroll
  for (int f = 0; f < 16; ++f) {
    const unsigned short* kp = &kh[(size_t)(nb + f * 16 + c) * 64 + g * 8];
    bf16x8 k0 = *(const bf16x8*)kp;
    bf16x8 k1 = *(const bf16x8*)(kp + 32);
    f32x4 z = {0.f, 0.f, 0.f, 0.f};
    z = __builtin_amdgcn_mfma_f32_16x16x32_bf16(qf[0], k0, z, 0, 0, 0);
    sc[f] = __builtin_amdgcn_mfma_f32_16x16x32_bf16(qf[1], k1, z, 0, 0, 0);
  }

  // scale + mask + row-max
  float vmax[4] = {-3e38f, -3e38f, -3e38f, -3e38f};
  unsigned mbits = 0;
#pragma unroll
  for (int f = 0; f < 16; ++f) {
    const int mk = mask[b * 2048 + nb + f * 16 + c];
    mbits |= (unsigned)(mk != 0) << f;
#pragma unroll
    for (int r = 0; r < 4; ++r) {
      float s = sc[f][r] * 0.125f;
      sc[f][r] = s;
      if (mk) vmax[r] = fmaxf(vmax[r], s);
    }
  }
#pragma unroll
  for (int d = 1; d < 16; d <<= 1)
#pragma unroll
    for (int r = 0; r < 4; ++r) vmax[r] = fmaxf(vmax[r], __shfl_xor(vmax[r], d, 64));
  if (c == 0) {
#pragma unroll
    for (int r = 0; r < 4; ++r) red_max[w][g * 4 + r] = vmax[r];
  }
  __syncthreads();
  float m4[4];
#pragma unroll
  for (int r = 0; r < 4; ++r) {
    float mm = red_max[0][g * 4 + r];
#pragma unroll
    for (int ww = 1; ww < 8; ++ww) mm = fmaxf(mm, red_max[ww][g * 4 + r]);
    m4[r] = mm;
  }
  // exp + row-sum
  float vsum[4] = {0.f, 0.f, 0.f, 0.f};
#pragma unroll
  for (int f = 0; f < 16; ++f) {
    const bool on = (mbits >> f) & 1;
#pragma unroll
    for (int r = 0; r < 4; ++r) {
      float p = on ? __expf(sc[f][r] - m4[r]) : 0.f;
      sc[f][r] = p;
      vsum[r] += p;
    }
  }
#pragma unroll
  for (int d = 1; d < 16; d <<= 1)
#pragma unroll
    for (int r = 0; r < 4; ++r) vsum[r] += __shfl_xor(vsum[r], d, 64);
  if (c == 0) {
#pragma unroll
    for (int r = 0; r < 4; ++r) red_sum[w][g * 4 + r] = vsum[r];
  }
  __syncthreads();
  float rn[4];
#pragma unroll
  for (int r = 0; r < 4; ++r) {
    float ss = 0.f;
#pragma unroll
    for (int ww = 0; ww < 8; ++ww) ss += red_sum[ww][g * 4 + r];
    rn[r] = (ss > 0.f) ? 1.0f / ss : 0.f;  // fully-masked row -> zeros (nan_to_num)
  }
  // normalize + write attn (fp32)
  float* arow = attn_out + ((size_t)(b * 16 + h) * 2048 + q0) * 2048;
#pragma unroll
  for (int f = 0; f < 16; ++f) {
#pragma unroll
    for (int r = 0; r < 4; ++r) {
      float p = sc[f][r] * rn[r];
      arow[(size_t)(g * 4 + r) * 2048 + nb + f * 16 + c] = p;
    }
  }
  asm volatile("s_waitcnt vmcnt(0)" ::: "memory");

  // PV: read back own strip (L2-hot) in A-fragment layout
  f32x4 hacc[4] = {};
#pragma unroll
  for (int ks = 0; ks < 8; ++ks) {
    const float* ap = arow + (size_t)c * 2048 + nb + ks * 32 + g * 8;
    float4 a0 = *(const float4*)ap;
    float4 a1 = *(const float4*)(ap + 4);
    union { bf16x8 v; unsigned short u[8]; } pa;
    pa.u[0] = f2bf(a0.x); pa.u[1] = f2bf(a0.y); pa.u[2] = f2bf(a0.z); pa.u[3] = f2bf(a0.w);
    pa.u[4] = f2bf(a1.x); pa.u[5] = f2bf(a1.y); pa.u[6] = f2bf(a1.z); pa.u[7] = f2bf(a1.w);
#pragma unroll
    for (int n = 0; n < 4; ++n) {
      bf16x8 bfv = *(const bf16x8*)&vth[(size_t)(n * 16 + c) * 2048 + nb + ks * 32 + g * 8];
      hacc[n] = __builtin_amdgcn_mfma_f32_16x16x32_bf16(pa.v, bfv, hacc[n], 0, 0, 0);
    }
  }
#pragma unroll
  for (int n = 0; n < 4; ++n)
#pragma unroll
    for (int r = 0; r < 4; ++r)
      hred[w][g * 4 + r][n * 16 + c] = hacc[n][r];
  __syncthreads();
  for (int e = tid; e < 1024; e += 512) {
    const int row = e >> 6, col = e & 63;
    float ssum = 0.f;
#pragma unroll
    for (int ww = 0; ww < 8; ++ww) ssum += hred[ww][row][col];
    concat[((size_t)(b * 2048 + q0 + row)) * 1024 + h * 64 + col] = f2bf(ssum);
  }
}

// ---------------- stage 4: output projection GEMM ----------------
__global__ __launch_bounds__(256) void gemm_out(
    const unsigned short* __restrict__ A,
    const unsigned short* __restrict__ W,
    const float* __restrict__ bo,
    float* __restrict__ out)
{
  __shared__ unsigned short aT[128 * 64];
  __shared__ unsigned short bT[128 * 64];
  const int tid = threadIdx.x;
  const int l = tid & 63, w = tid >> 6;
  const int wr = (w >> 1) * 64, wc = (w & 1) * 64;
  const int g = l >> 4, c = l & 15;
  const int tM = blockIdx.x, tN = blockIdx.y;
  const int srow = tid >> 3, scol = (tid & 7) * 8;
  const unsigned short* ga = A + (size_t)(tM * 128 + srow) * 1024 + scol;
  const unsigned short* gb = W + (size_t)(tN * 128 + srow) * 1024 + scol;
  f32x4 acc[4][4] = {};
  for (int kt = 0; kt < 16; ++kt) {
    u16x8 av[4], bv[4];
#pragma unroll
    for (int i = 0; i < 4; ++i) {
      av[i] = *(const u16x8*)(ga + kt * 64 + (size_t)i * 32 * 1024);
      bv[i] = *(const u16x8*)(gb + kt * 64 + (size_t)i * 32 * 1024);
    }
    __syncthreads();
#pragma unroll
    for (int i = 0; i < 4; ++i) {
      *(u16x8*)&aT[(srow + i * 32) * 64 + scol] = av[i];
      *(u16x8*)&bT[(srow + i * 32) * 64 + scol] = bv[i];
    }
    __syncthreads();
#pragma unroll
    for (int kk = 0; kk < 2; ++kk) {
      bf16x8 af[4], bf[4];
#pragma unroll
      for (int m = 0; m < 4; ++m)
        af[m] = *(const bf16x8*)&aT[(wr + m * 16 + c) * 64 + kk * 32 + g * 8];
#pragma unroll
      for (int n = 0; n < 4; ++n)
        bf[n] = *(const bf16x8*)&bT[(wc + n * 16 + c) * 64 + kk * 32 + g * 8];
#pragma unroll
      for (int m = 0; m < 4; ++m)
#pragma unroll
        for (int n = 0; n < 4; ++n)
          acc[m][n] = __builtin_amdgcn_mfma_f32_16x16x32_bf16(af[m], bf[n], acc[m][n], 0, 0, 0);
    }
  }
#pragma unroll
  for (int m = 0; m < 4; ++m) {
#pragma unroll
    for (int n = 0; n < 4; ++n) {
      const int row0 = tM * 128 + wr + m * 16 + g * 4;
      const int ncol = tN * 128 + wc + n * 16 + c;
      const float bias = bo[ncol];
#pragma unroll
      for (int r = 0; r < 4; ++r)
        out[(size_t)(row0 + r) * 1024 + ncol] = acc[m][n][r] + bias;
    }
  }
}

// ---------------- launch ----------------
extern "C" void kernel_launch(void* const* d_in, const int* in_sizes, int n_in,
                              void* d_out, int out_size, void* d_ws, size_t ws_size,
                              hipStream_t stream) {
  const float* x    = (const float*)d_in[0];
  const int*   mask = (const int*)d_in[1];
  const float* wq   = (const float*)d_in[2];
  const float* wk   = (const float*)d_in[3];
  const float* wv   = (const float*)d_in[4];
  const float* wo   = (const float*)d_in[5];
  const float* bo   = (const float*)d_in[6];

  // workspace layout (ushort elements)
  unsigned short* ws = (unsigned short*)d_ws;
  if (ws_size < (size_t)92274688) return;  // need ~88 MB
  unsigned short* x_bf   = ws;                 // 8192*1024
  unsigned short* w_all  = ws + 8388608;       // 3072*1024
  unsigned short* wo_bf  = ws + 11534336;      // 1024*1024
  unsigned short* qm     = ws + 12582912;      // [B,H,S,64]
  unsigned short* km     = ws + 20971520;      // [B,H,S,64]
  unsigned short* vt     = ws + 29360128;      // [B,H,64,S]
  unsigned short* concat = ws + 37748736;      // [8192,1024]

  float* out  = (float*)d_out;
  float* attn = out + 8388608;

  cast_kernel<<<2048, 256, 0, stream>>>(x, x_bf, 2097152);
  cast_kernel<<<1024, 256, 0, stream>>>(wq, w_all, 262144);
  cast_kernel<<<1024, 256, 0, stream>>>(wk, w_all + 1048576, 262144);
  cast_kernel<<<1024, 256, 0, stream>>>(wv, w_all + 2097152, 262144);
  cast_kernel<<<1024, 256, 0, stream>>>(wo, wo_bf, 262144);

  gemm_qkv<<<dim3(64, 24), 256, 0, stream>>>(x_bf, w_all, qm, km, vt);
  attn_kernel<<<dim3(128, 16, 4), 512, 0, stream>>>(qm, km, vt, mask, attn, concat);
  gemm_out<<<dim3(64, 8), 256, 0, stream>>>(concat, wo_bf, bo, out);
}